// Round 10
// baseline (110.294 us; speedup 1.0000x reference)
//
#include <hip/hip_runtime.h>

#define N_SERIES 1024
#define N_TIME 600
#define INPUT_SIZE 168
#define OUTPUT_SIZE 24
#define N_S 4
#define SEAS 24
#define N_WINDOWS (N_TIME - INPUT_SIZE - OUTPUT_SIZE + 1) /* 409 */
#define SEAS_LEN (N_TIME + SEAS)                          /* 624 */

#define INS_ELEMS (N_WINDOWS * N_SERIES * (INPUT_SIZE + N_S)) /* 72,036,352 */
#define OUTS_ELEMS (N_WINDOWS * N_SERIES * OUTPUT_SIZE)       /* 10,051,584 */
#define LEV_ELEMS (N_SERIES * N_TIME)
#define SEAS_ELEMS (N_SERIES * SEAS_LEN)

#define NQ_OUTS (OUTS_ELEMS / 4)              /* 2,512,896 */
#define NQ_INS43 (N_WINDOWS * N_SERIES * 43)  /* 18,009,088 */
#define INS_SLICE (NQ_INS43 / 8)              /* 2,251,136 (43|SLICE, 64|SLICE) */

#define SCAN_BLOCKS 16
#define SCAN_T 64
#define COPY_BLOCKS 2032
#define INS_BLOCKS 2048
#define WS_NEEDED (2u * LEV_ELEMS * sizeof(float)) /* tbl + llv = 4.9 MB */

typedef float f4 __attribute__((ext_vector_type(4)));

// Single-wave LDS phase fence: LDS ops within one wave retire in order, so no
// s_barrier / vmcnt drain — only a compiler scheduling fence between phases.
#define WAVE_FENCE()                                   \
    do {                                               \
        __builtin_amdgcn_wave_barrier();               \
        asm volatile("" ::: "memory");                 \
    } while (0)

// ---------------------------------------------------------------------------
// Kernel 1 (fused): blocks [0,16): exponential-smoothing scan (1 wave/block,
// register ring buffer, LDS-staged coalesced stores, no barriers).
// blocks [16,...): outsample window copy, nontemporal.
// ---------------------------------------------------------------------------
__global__ __launch_bounds__(SCAN_T) void scan_copy_kernel(
    const float* __restrict__ y, const float* __restrict__ embeds,
    const int* __restrict__ idxs, float* __restrict__ levels,
    float* __restrict__ seas1, f4* __restrict__ out_outs)
{
    __shared__ float b_lev[SCAN_T][25];
    __shared__ float b_sea[SCAN_T][25];

    if (blockIdx.x < SCAN_BLOCKS) {
        const int lane = threadIdx.x;
        const int s0 = blockIdx.x * SCAN_T;
        const int s = s0 + lane;
        const int row = idxs[s];
        const float* e = embeds + row * (2 + SEAS);

        const float lev_sms = 1.0f / (1.0f + __expf(-e[0]));
        const float seas_sms = 1.0f / (1.0f + __expf(-e[1]));
        const float one_m_lev = 1.0f - lev_sms;
        const float one_m_seas = 1.0f - seas_sms;

        const float* yrow = y + s * N_TIME;
        const f4* yv4 = (const f4*)yrow; // row stride 2400B keeps 16B align

        f4 cur[6], nxt[6];
#pragma unroll
        for (int i = 0; i < 6; ++i) cur[i] = yv4[i];

        float sb[SEAS];
#pragma unroll
        for (int j = 0; j < SEAS; ++j) {
            float v = __expf(e[2 + j]);
            sb[j] = v;
            b_sea[lane][j] = v;
        }
        WAVE_FENCE();
        // init seasonality cols 0..23: cooperative f4 stores (aligned)
#pragma unroll
        for (int k4 = 0; k4 < 6; ++k4) {
            int q4 = lane + k4 * SCAN_T;
            int r = q4 / 6;
            int c4 = q4 - r * 6;
            int cc = c4 * 4;
            f4 v = {b_sea[r][cc], b_sea[r][cc + 1], b_sea[r][cc + 2],
                    b_sea[r][cc + 3]};
            *(f4*)(seas1 + (s0 + r) * SEAS_LEN + cc) = v;
        }
        seas1[s * SEAS_LEN + SEAS] = sb[0]; // col 24 = rolled init_seas[0]
        float lev = __fdividef(cur[0].x, sb[0]);
        levels[s * N_TIME] = lev;
        WAVE_FENCE(); // b_sea reused below

        // ---- chunk 0: t = 1..23 (ring index = t), scalar store path ----
        {
#pragma unroll
            for (int i = 0; i < 6; ++i) nxt[i] = yv4[6 + i];
#pragma unroll
            for (int j = 0; j < 23; ++j) {
                const int t = j + 1;
                float yt = cur[t >> 2][t & 3];
                float st = sb[t];
                float q1 = __fdividef(yt, st);
                float newlev = lev_sms * q1 + one_m_lev * lev;
                float news =
                    seas_sms * __fdividef(yt, newlev) + one_m_seas * st;
                lev = newlev;
                sb[t] = news;
                b_lev[lane][j] = newlev;
                b_sea[lane][j] = news;
            }
            WAVE_FENCE();
#pragma unroll
            for (int k = 0; k < 24; ++k) {
                int i = lane + k * SCAN_T;
                int r = i / 24;
                int col = i - r * 24;
                if (col < 23) {
                    int sr = s0 + r;
                    levels[sr * N_TIME + 1 + col] = b_lev[r][col];
                    seas1[sr * SEAS_LEN + 25 + col] = b_sea[r][col];
                }
            }
            WAVE_FENCE();
#pragma unroll
            for (int i = 0; i < 6; ++i) cur[i] = nxt[i];
        }

        // ---- chunks c = 1..24: t = 24c + j, ring index = j ----
#pragma unroll 1
        for (int c = 1; c < 25; ++c) {
            const int t0 = 24 * c;
            if (c < 24) {
                const f4* p = (const f4*)(yrow + 24 * (c + 1));
#pragma unroll
                for (int i = 0; i < 6; ++i) nxt[i] = p[i];
            }
#pragma unroll
            for (int j = 0; j < 24; ++j) {
                float yt = cur[j >> 2][j & 3];
                float st = sb[j];
                float q1 = __fdividef(yt, st);
                float newlev = lev_sms * q1 + one_m_lev * lev;
                float news =
                    seas_sms * __fdividef(yt, newlev) + one_m_seas * st;
                lev = newlev;
                sb[j] = news;
                b_lev[lane][j] = newlev;
                b_sea[lane][j] = news;
            }
            WAVE_FENCE();
            // cooperative f4 stores: t0 = 24c -> 96c bytes, 16B-aligned
#pragma unroll
            for (int k4 = 0; k4 < 6; ++k4) {
                int q4 = lane + k4 * SCAN_T;
                int r = q4 / 6;
                int c4 = q4 - r * 6;
                int sr = s0 + r;
                int cc = c4 * 4;
                f4 vl = {b_lev[r][cc], b_lev[r][cc + 1], b_lev[r][cc + 2],
                         b_lev[r][cc + 3]};
                *(f4*)(levels + sr * N_TIME + t0 + cc) = vl;
                f4 vs = {b_sea[r][cc], b_sea[r][cc + 1], b_sea[r][cc + 2],
                         b_sea[r][cc + 3]};
                *(f4*)(seas1 + sr * SEAS_LEN + SEAS + t0 + cc) = vs;
            }
            WAVE_FENCE();
#pragma unroll
            for (int i = 0; i < 6; ++i) cur[i] = nxt[i];
        }
    } else {
        // copy role: outsample windows — dense wave-aligned, nontemporal
        int idx = (blockIdx.x - SCAN_BLOCKS) * SCAN_T + threadIdx.x;
        const int stride = (gridDim.x - SCAN_BLOCKS) * SCAN_T;
        for (; idx < NQ_OUTS; idx += stride) {
            int rowq = idx / 6;
            int j4 = idx - rowq * 6;
            int w = rowq >> 10;
            int s = rowq & 1023;
            const float* yp = y + s * N_TIME + w + INPUT_SIZE + j4 * 4;
            f4 v = {yp[0], yp[1], yp[2], yp[3]};
            __builtin_nontemporal_store(v, &out_outs[idx]);
        }
    }
}

// ---------------------------------------------------------------------------
// Kernel 2: full-GPU parallel log pass from y + d_out tables:
//   tbl[s][t] = log(y/seas1), llv[s][t] = log(levels).
// ---------------------------------------------------------------------------
__global__ __launch_bounds__(256) void logpass_kernel(
    const float* __restrict__ y, const float* __restrict__ levels,
    const float* __restrict__ seas1, float* __restrict__ tbl,
    float* __restrict__ llv)
{
    int i = blockIdx.x * 256 + threadIdx.x; // f4 index over [0, 153600)
    int sr = i / 150;
    int c = i - sr * 150;
    f4 a = *((const f4*)(y + sr * N_TIME) + c);
    f4 se = *((const f4*)(seas1 + sr * SEAS_LEN) + c); // 2496B rows, aligned
    f4 l = *((const f4*)(levels + sr * N_TIME) + c);
    f4 ta, tl;
    ta.x = __logf(__fdividef(a.x, se.x));
    ta.y = __logf(__fdividef(a.y, se.y));
    ta.z = __logf(__fdividef(a.z, se.z));
    ta.w = __logf(__fdividef(a.w, se.w));
    tl.x = __logf(l.x);
    tl.y = __logf(l.y);
    tl.z = __logf(l.z);
    tl.w = __logf(l.w);
    ((f4*)tbl)[i] = ta;
    ((f4*)llv)[i] = tl;
}

// ---------------------------------------------------------------------------
// Kernel 3 (fast path): insample rows incl. static column. XCD-clustered
// 1/8 q-slices. MANUAL x4 UNROLL with batched loads: issue ~20 loads for 4
// stride-iterations, then compute + nontemporal-store 4 — quadruples
// bytes-in-flight per wave (the R9 loop's divergent branch + store blocked
// compiler pipelining, capping MLP at ~5 loads/wave -> ~3.5 TB/s).
// 65536 = 43*1524 + 4 gives the incremental (rowq, e4) step.
// ---------------------------------------------------------------------------
__global__ __launch_bounds__(256) void ins_kernel(
    const float* __restrict__ tbl, const float* __restrict__ llv,
    const float* __restrict__ s_matrix, f4* __restrict__ out_ins)
{
    const f4* sm4 = (const f4*)s_matrix;
    const int xcd = blockIdx.x & 7;
    const int lb = blockIdx.x >> 3; // 0..255
    const int qend = (xcd + 1) * INS_SLICE;
    const int stride = (INS_BLOCKS / 8) * 256; /* 65536 */
    int q = xcd * INS_SLICE + lb * 256 + (int)threadIdx.x;
    int rowq = q / 43;
    int e4 = q - rowq * 43;

    while (q + 3 * stride < qend) {
        int rq[4], ee[4];
        rq[0] = rowq;
        ee[0] = e4;
#pragma unroll
        for (int k = 1; k < 4; ++k) {
            rq[k] = rq[k - 1] + 1524;
            ee[k] = ee[k - 1] + 4;
            if (ee[k] >= 43) {
                ee[k] -= 43;
                rq[k] += 1;
            }
        }
        f4 v[4];
        float a[4][4];
        float lv[4];
        // phase 1: issue ALL loads (independent, batched)
#pragma unroll
        for (int k = 0; k < 4; ++k) {
            int w = rq[k] >> 10;
            int s = rq[k] & 1023;
            if (ee[k] == 42) {
                v[k] = sm4[s];
            } else {
                const float* tp = tbl + s * N_TIME + w + ee[k] * 4;
                a[k][0] = tp[0];
                a[k][1] = tp[1];
                a[k][2] = tp[2];
                a[k][3] = tp[3];
                lv[k] = llv[s * N_TIME + w + INPUT_SIZE - 1];
            }
        }
        // phase 2: compute + store
#pragma unroll
        for (int k = 0; k < 4; ++k) {
            if (ee[k] != 42) {
                v[k].x = a[k][0] - lv[k];
                v[k].y = a[k][1] - lv[k];
                v[k].z = a[k][2] - lv[k];
                v[k].w = a[k][3] - lv[k];
            }
            __builtin_nontemporal_store(v[k], &out_ins[q + k * stride]);
        }
        rowq = rq[3] + 1524;
        e4 = ee[3] + 4;
        if (e4 >= 43) {
            e4 -= 43;
            rowq += 1;
        }
        q += 4 * stride;
    }
    // scalar tail (<= 3 iterations + ragged slice end)
    while (q < qend) {
        int w = rowq >> 10;
        int s = rowq & 1023;
        f4 v;
        if (e4 == 42) {
            v = sm4[s];
        } else {
            int t = w + e4 * 4;
            const float* tp = tbl + s * N_TIME + t;
            float lv = llv[s * N_TIME + w + INPUT_SIZE - 1];
            v.x = tp[0] - lv;
            v.y = tp[1] - lv;
            v.z = tp[2] - lv;
            v.w = tp[3] - lv;
        }
        __builtin_nontemporal_store(v, &out_ins[q]);
        rowq += 1524;
        e4 += 4;
        if (e4 >= 43) {
            e4 -= 43;
            rowq += 1;
        }
        q += stride;
    }
}

// Fallback (ws too small): compute logs on the fly, same XCD clustering.
__global__ __launch_bounds__(256) void ins_kernel_fb(
    const float* __restrict__ y, const float* __restrict__ levels,
    const float* __restrict__ seas1, const float* __restrict__ s_matrix,
    f4* __restrict__ out_ins)
{
    const f4* sm4 = (const f4*)s_matrix;
    const int xcd = blockIdx.x & 7;
    const int lb = blockIdx.x >> 3;
    const int qend = (xcd + 1) * INS_SLICE;
    const int stride = (INS_BLOCKS / 8) * 256;
    for (int q = xcd * INS_SLICE + lb * 256 + (int)threadIdx.x; q < qend;
         q += stride) {
        int rowq = q / 43;
        int e4 = q - rowq * 43;
        int w = rowq >> 10;
        int s = rowq & 1023;
        f4 v;
        if (e4 == 42) {
            v = sm4[s];
        } else {
            int t = w + e4 * 4;
            float lev = levels[s * N_TIME + w + INPUT_SIZE - 1];
            const float* yp = y + s * N_TIME + t;
            const float* sp = seas1 + s * SEAS_LEN + t;
            float vv[4];
#pragma unroll
            for (int j = 0; j < 4; ++j)
                vv[j] = __logf(__fdividef(yp[j], lev * sp[j]));
            v.x = vv[0]; v.y = vv[1]; v.z = vv[2]; v.w = vv[3];
        }
        __builtin_nontemporal_store(v, &out_ins[q]);
    }
}

extern "C" void kernel_launch(void* const* d_in, const int* in_sizes, int n_in,
                              void* d_out, int out_size, void* d_ws, size_t ws_size,
                              hipStream_t stream) {
    const float* y      = (const float*)d_in[0];
    const float* sm     = (const float*)d_in[1];
    const float* embeds = (const float*)d_in[2];
    const int*   idxs   = (const int*)d_in[3];

    float* out      = (float*)d_out;
    float* out_ins  = out;
    float* out_outs = out + INS_ELEMS;
    float* out_lev  = out + INS_ELEMS + OUTS_ELEMS;
    float* out_seas = out_lev + LEV_ELEMS;

    float* tbl = (float*)d_ws;
    float* llv = tbl + LEV_ELEMS;
    const int have_ws = (ws_size >= (size_t)WS_NEEDED) ? 1 : 0;

    scan_copy_kernel<<<SCAN_BLOCKS + COPY_BLOCKS, SCAN_T, 0, stream>>>(
        y, embeds, idxs, out_lev, out_seas, (f4*)out_outs);
    if (have_ws) {
        logpass_kernel<<<LEV_ELEMS / 4 / 256, 256, 0, stream>>>(
            y, out_lev, out_seas, tbl, llv);
        ins_kernel<<<INS_BLOCKS, 256, 0, stream>>>(tbl, llv, sm,
                                                   (f4*)out_ins);
    } else {
        ins_kernel_fb<<<INS_BLOCKS, 256, 0, stream>>>(y, out_lev, out_seas,
                                                      sm, (f4*)out_ins);
    }
}